// Round 2
// baseline (297.724 us; speedup 1.0000x reference)
//
#include <hip/hip_runtime.h>

// LRMU scan collapsed to out = U_rev^T @ P with P[j] = b·A^j via log-doubling.
// R2: single persistent kernel (256 blocks = 1/CU, co-resident) with an
// atomic grid barrier between the 9 sequential phases, replacing 10 launches.
// All fp32 (~600 MFLOP total).

#define SEQ_T 256
#define NB 16
#define DIM 128
#define ORD 256
#define BMROWS 2048
#define NBLK 256

// float offsets into ws
#define OFF_U 0                         // U[t][bm]: 256*2048
#define OFF_P (SEQ_T * BMROWS)          // P[j][o]: 256*256
#define OFF_A0 (OFF_P + ORD * ORD)      // A-power ping
#define OFF_A1 (OFF_A0 + ORD * ORD)     // A-power pong
#define OFF_BAR (OFF_A1 + ORD * ORD)    // 2 x u32 barrier state

__device__ __forceinline__ void grid_barrier(unsigned* bar) {
  __syncthreads();
  if (threadIdx.x == 0) {
    __threadfence();                       // release prior writes
    unsigned g = atomicAdd(&bar[1], 0u);   // read generation BEFORE arriving
    if (atomicAdd(&bar[0], 1u) == NBLK - 1) {
      atomicExch(&bar[0], 0u);             // reset count, then release
      atomicAdd(&bar[1], 1u);
    } else {
      while (atomicAdd(&bar[1], 0u) == g) __builtin_amdgcn_s_sleep(2);
    }
    __threadfence();                       // acquire other blocks' writes
  }
  __syncthreads();
}

__global__ __launch_bounds__(256) void lrmu_all(
    const float* __restrict__ x, const float* __restrict__ K,
    const float* __restrict__ A, const float* __restrict__ Bm,
    float* __restrict__ out, float* __restrict__ ws) {
  __shared__ __align__(16) float smem[4096];  // 16 KB, reused per phase
  float* U = ws + OFF_U;
  float* P = ws + OFF_P;
  float* A0 = ws + OFF_A0;
  float* A1 = ws + OFF_A1;
  unsigned* bar = (unsigned*)(ws + OFF_BAR);
  const int blk = blockIdx.x, tid = threadIdx.x;

  // ---- Phase U: U[t][bm] = sum_d x[b][t][d] * K[d][m];  P[0] = b ----
  {
    int b = blk >> 4, tc = blk & 15;  // 16 t-steps per block
    float* xs = smem;                 // [16][128]
    for (int idx = tid; idx < 16 * DIM; idx += 256)
      xs[idx] = x[(b * SEQ_T + tc * 16) * DIM + idx];
    __syncthreads();
    int m = tid & 127, th = tid >> 7;  // th in {0,1}: 8 t each
    float acc[8] = {};
#pragma unroll 4
    for (int d = 0; d < DIM; ++d) {
      float kv = K[d * DIM + m];  // coalesced per wave, L2-resident
#pragma unroll
      for (int r = 0; r < 8; ++r)
        acc[r] = fmaf(xs[(th * 8 + r) * DIM + d], kv, acc[r]);
    }
#pragma unroll
    for (int r = 0; r < 8; ++r)
      U[(tc * 16 + th * 8 + r) * BMROWS + b * DIM + m] = acc[r];
    if (blk == 0) P[tid] = Bm[tid];  // ORD == 256 == blockDim
  }
  grid_barrier(bar);

  // ---- 8 doubling steps: Anew = Aold^2 (128 blks), P[half+r] = P[r]@Aold ----
  for (int k = 0; k < 8; ++k) {
    const float* Aold = (k == 0) ? A : ((k & 1) ? A0 : A1);
    float* Anew = (k & 1) ? A1 : A0;
    int half = 1 << k;
    int nsq = (k < 7) ? 128 : 0;        // k=7 needs no squaring
    int rt = (k < 7) ? 8 : 2;           // doubling row-tile
    int ndb = ((half + rt - 1) / rt) * 4;
    const float* L = nullptr;
    float* C = nullptr;
    int nrows = 0, c0 = 0;
    if (blk < nsq) {                    // squaring: 8 rows x 64 cols
      int rg = blk >> 2;
      c0 = (blk & 3) * 64;
      L = Aold + rg * 8 * ORD;
      C = Anew + rg * 8 * ORD;
      nrows = 8;
    } else if (blk < nsq + ndb) {       // doubling: rt rows x 64 cols
      int idx = blk - nsq;
      int rg = idx >> 2;
      c0 = (idx & 3) * 64;
      L = P + rg * rt * ORD;
      C = P + (half + rg * rt) * ORD;
      nrows = half - rg * rt;
      if (nrows > rt) nrows = rt;
    }
    if (L) {
      float* ls = smem;          // [8][256] left rows
      float* red = smem + 2048;  // [4][8][64] partials
      for (int idx = tid; idx < 8 * ORD; idx += 256) {
        int r = idx >> 8;
        ls[idx] = (r < nrows) ? L[idx] : 0.f;  // rows contiguous: L[idx] ok
      }
      __syncthreads();
      int c = tid & 63, q = tid >> 6;  // wave q sums i in [q*64, q*64+64)
      float acc[8] = {};
      const float* col = Aold + c0 + c;
#pragma unroll 8
      for (int i2 = 0; i2 < 64; ++i2) {
        int i = q * 64 + i2;
        float av = col[i * ORD];  // coalesced 64-wide per wave
#pragma unroll
        for (int r = 0; r < 8; ++r)
          acc[r] = fmaf(ls[r * ORD + i], av, acc[r]);  // LDS broadcast
      }
#pragma unroll
      for (int r = 0; r < 8; ++r) red[(q * 8 + r) * 64 + c] = acc[r];
      __syncthreads();
      int rr = tid >> 6;
#pragma unroll
      for (int rh = 0; rh < 2; ++rh) {
        int r = rr + rh * 4;
        if (r < nrows) {
          float s = red[r * 64 + c] + red[(8 + r) * 64 + c] +
                    red[(16 + r) * 64 + c] + red[(24 + r) * 64 + c];
          C[r * ORD + c0 + c] = s;
        }
      }
    }
    grid_barrier(bar);
  }

  // ---- Phase out: out[bm][o] = sum_t U[t][bm] * P[255-t][o] ----
  {
    float* us = smem;  // [256][8]
    int bm0 = blk * 8;
    for (int idx = tid; idx < SEQ_T * 8; idx += 256) {
      int t = idx >> 3, r = idx & 7;
      us[idx] = U[t * BMROWS + bm0 + r];
    }
    __syncthreads();
    float acc[8] = {};
    int c = tid;
#pragma unroll 8
    for (int t = 0; t < SEQ_T; ++t) {
      float pv = P[(SEQ_T - 1 - t) * ORD + c];  // coalesced, L2-resident
      const float4 u0 = *(const float4*)&us[t * 8];      // LDS broadcast
      const float4 u1 = *(const float4*)&us[t * 8 + 4];
      acc[0] = fmaf(u0.x, pv, acc[0]);
      acc[1] = fmaf(u0.y, pv, acc[1]);
      acc[2] = fmaf(u0.z, pv, acc[2]);
      acc[3] = fmaf(u0.w, pv, acc[3]);
      acc[4] = fmaf(u1.x, pv, acc[4]);
      acc[5] = fmaf(u1.y, pv, acc[5]);
      acc[6] = fmaf(u1.z, pv, acc[6]);
      acc[7] = fmaf(u1.w, pv, acc[7]);
    }
#pragma unroll
    for (int r = 0; r < 8; ++r) out[(bm0 + r) * ORD + c] = acc[r];
  }
}

extern "C" void kernel_launch(void* const* d_in, const int* in_sizes, int n_in,
                              void* d_out, int out_size, void* d_ws,
                              size_t ws_size, hipStream_t stream) {
  const float* x = (const float*)d_in[0];   // (16,256,128)
  const float* K = (const float*)d_in[1];   // (128,128)
  const float* A = (const float*)d_in[2];   // (256,256)
  const float* Bm = (const float*)d_in[3];  // (256,)
  float* out = (float*)d_out;               // (16, 32768)
  float* ws = (float*)d_ws;

  // zero the barrier state (ws is re-poisoned 0xAA before every launch)
  hipMemsetAsync(ws + OFF_BAR, 0, 2 * sizeof(unsigned), stream);
  lrmu_all<<<NBLK, 256, 0, stream>>>(x, K, A, Bm, out, ws);
}